// Round 6
// baseline (579.487 us; speedup 1.0000x reference)
//
#include <hip/hip_runtime.h>
#include <hip/hip_bf16.h>
#include <stdint.h>

// ---------------- problem constants ----------------
#define NH     16
#define QRANK  1536
#define NOPE_  128
#define QKHD   192
#define NMERGE 1728   // QRANK + QKHD
#define B_     2
#define S_     2048
#define MAXSEQ 2048
#define EPS_   1e-6f
#define SCALE_ 0.07216878364870322f  // 192^-0.5

typedef __attribute__((ext_vector_type(4))) float f32x4;
typedef __attribute__((ext_vector_type(8))) short short8;
typedef __attribute__((ext_vector_type(4))) short short4v;

__device__ inline short f2bf(float f){
  uint32_t u = __builtin_bit_cast(uint32_t, f);
  uint32_t r = (u + 0x7FFFu + ((u >> 16) & 1u)) >> 16;
  return (short)(uint16_t)r;
}
__device__ inline float bf2f(short s){
  uint32_t u = ((uint32_t)(uint16_t)s) << 16;
  return __builtin_bit_cast(float, u);
}
__device__ inline void gload16(const short* g, short* l){
  __builtin_amdgcn_global_load_lds((const __attribute__((address_space(1))) void*)g,
                                   (__attribute__((address_space(3))) void*)l, 16, 0, 0);
}

// ---------------- f32 -> bf16 convert (vectorized) ----------------
__global__ void k_f2b(const float* __restrict__ in, short* __restrict__ out, long n){
  long i = ((long)blockIdx.x * blockDim.x + threadIdx.x) * 4;
  long stride = (long)gridDim.x * blockDim.x * 4;
  for(; i < n; i += stride){
    float4 v = *reinterpret_cast<const float4*>(in + i);
    short4v o;
    o.x = f2bf(v.x); o.y = f2bf(v.y); o.z = f2bf(v.z); o.w = f2bf(v.w);
    *reinterpret_cast<short4v*>(out + i) = o;
  }
}

// ---------------- m97 GEMM: C[M][N] = A[M][K]@B[N][K]^T + bias ----------------
template<int BN, bool OUT_BF16>
__global__ __launch_bounds__(256)
void k_gemm97(const short* __restrict__ A, const short* __restrict__ Bm,
              const float* __restrict__ bias, float biasScale,
              void* __restrict__ Cp, int M, int N, int K, int ldc)
{
  constexpr int WN = BN / 2, FN = WN / 16;
  __shared__ short As[128 * 32];
  __shared__ short Bs[BN * 32];
  const int tid = threadIdx.x;
  const int l = tid & 63, w = tid >> 6;
  const int wr = w >> 1, wc = w & 1;
  const long m0 = (long)blockIdx.x * 128;
  const long n0 = (long)blockIdx.y * BN;
  const int lrow = l & 15, lk8 = (l >> 4) * 8;

  int ciA0 = (w*2 + 0)*64 + l, ciA1 = (w*2 + 1)*64 + l;
  const short* a0 = &A[(m0 + (ciA0 >> 2))*(long)K + (ciA0 & 3)*8];
  const short* a1 = &A[(m0 + (ciA1 >> 2))*(long)K + (ciA1 & 3)*8];
  short* lA0 = &As[(w*2 + 0)*512];
  short* lA1 = &As[(w*2 + 1)*512];

  const short* b0; const short* b1 = nullptr;
  short* lB0; short* lB1 = nullptr;
  if constexpr (BN == 128){
    int ciB0 = (w*2 + 0)*64 + l, ciB1 = (w*2 + 1)*64 + l;
    b0 = &Bm[(n0 + (ciB0 >> 2))*(long)K + (ciB0 & 3)*8];
    b1 = &Bm[(n0 + (ciB1 >> 2))*(long)K + (ciB1 & 3)*8];
    lB0 = &Bs[(w*2 + 0)*512];
    lB1 = &Bs[(w*2 + 1)*512];
  } else {
    int ciB = w*64 + l;
    b0 = &Bm[(n0 + (ciB >> 2))*(long)K + (ciB & 3)*8];
    lB0 = &Bs[w*512];
  }

  f32x4 acc[4][FN];
  #pragma unroll
  for(int m = 0; m < 4; m++)
    #pragma unroll
    for(int n = 0; n < FN; n++) acc[m][n] = (f32x4)0.0f;

  for(int kt = 0; kt < K; kt += 32){
    gload16(a0 + kt, lA0);
    gload16(a1 + kt, lA1);
    gload16(b0 + kt, lB0);
    if constexpr (BN == 128) gload16(b1 + kt, lB1);
    __syncthreads();
    short8 af[4], bfv[FN];
    #pragma unroll
    for(int m = 0; m < 4; m++)
      af[m] = *reinterpret_cast<const short8*>(&As[(wr*64 + m*16 + lrow)*32 + lk8]);
    #pragma unroll
    for(int n = 0; n < FN; n++)
      bfv[n] = *reinterpret_cast<const short8*>(&Bs[(wc*WN + n*16 + lrow)*32 + lk8]);
    #pragma unroll
    for(int m = 0; m < 4; m++)
      #pragma unroll
      for(int n = 0; n < FN; n++)
        acc[m][n] = __builtin_amdgcn_mfma_f32_16x16x32_bf16(af[m], bfv[n], acc[m][n], 0, 0, 0);
    __syncthreads();
  }
  #pragma unroll
  for(int m = 0; m < 4; m++){
    int row_l = wr*64 + m*16 + (l >> 4)*4;
    #pragma unroll
    for(int n = 0; n < FN; n++){
      int col = (int)n0 + wc*WN + n*16 + lrow;
      float bv = bias ? bias[col]*biasScale : 0.0f;
      #pragma unroll
      for(int r = 0; r < 4; r++){
        long row = m0 + row_l + r;
        float v = acc[m][n][r] + bv;
        if constexpr (OUT_BF16) ((short*)Cp)[row*(long)ldc + col] = f2bf(v);
        else                    ((float*)Cp)[row*(long)ldc + col] = v;
      }
    }
  }
}

// ---------------- RMS norm over 1536 (rows stride 1728), + input bias ---------
__global__ __launch_bounds__(256)
void k_rms_q(const float* __restrict__ in, const float* __restrict__ bias,
             const float* __restrict__ w, short* __restrict__ out)
{
  const int row = blockIdx.x;
  const int tid = threadIdx.x;
  const float* p = in + (long)row * NMERGE;
  float v[6]; float ss = 0.0f;
  #pragma unroll
  for(int i = 0; i < 6; i++){
    int c = tid + 256*i;
    v[i] = p[c] + bias[c];
    ss += v[i]*v[i];
  }
  #pragma unroll
  for(int off = 1; off < 64; off <<= 1) ss += __shfl_xor(ss, off);
  __shared__ float red[4];
  if((tid & 63) == 0) red[tid >> 6] = ss;
  __syncthreads();
  ss = red[0] + red[1] + red[2] + red[3];
  float scale = rsqrtf(ss / (float)QRANK + EPS_);
  #pragma unroll
  for(int i = 0; i < 6; i++){
    int c = tid + 256*i;
    out[(long)row*QRANK + c] = f2bf(v[i] * scale * w[c]);
  }
}

// ---------------- q assemble (vectorized short4): split nope / rope pe ----------
__global__ __launch_bounds__(256)
void k_qassemble(const short* __restrict__ q, const float* __restrict__ freqs,
                 short* __restrict__ qn, short* __restrict__ qfull)
{
  long idx = (long)blockIdx.x*256 + threadIdx.x;   // < 65536*48
  long hr = idx / 48; int r = (int)(idx % 48);
  long bs = hr >> 4; int h = (int)(hr & 15);
  int s = (int)(bs & (S_ - 1));
  if(r < 32){
    short4v v = *reinterpret_cast<const short4v*>(&q[bs*3072 + h*QKHD + r*4]);
    *reinterpret_cast<short4v*>(&qn[hr*128 + r*4]) = v;
  } else {
    int c = r - 32;   // 0..15
    short4v v = *reinterpret_cast<const short4v*>(&q[bs*3072 + h*QKHD + 128 + c*4]);
    float a0 = bf2f(v.x), b0 = bf2f(v.y), a1 = bf2f(v.z), b1 = bf2f(v.w);
    int p0 = s*32 + c*2, p1 = p0 + 1;
    float cs0 = freqs[p0*2], sn0 = freqs[p0*2 + 1];
    float cs1 = freqs[p1*2], sn1 = freqs[p1*2 + 1];
    short4v o;
    o.x = f2bf(a0*cs0 - b0*sn0); o.y = f2bf(a0*sn0 + b0*cs0);
    o.z = f2bf(a1*cs1 - b1*sn1); o.w = f2bf(a1*sn1 + b1*cs1);
    *reinterpret_cast<short4v*>(&qfull[hr*QKHD + 128 + c*4]) = o;
  }
}

// ---------------- kv: +bias, RMS(192), rope(last 64), cache merge --------------
// kvf = merged-GEMM output + col offset 1536, row stride 1728.
__global__ __launch_bounds__(256)
void k_kvproc(const float* __restrict__ kvf, const float* __restrict__ kvb,
              const float* __restrict__ w, const float* __restrict__ freqs,
              const float* __restrict__ cache, const int* __restrict__ sp_ptr,
              short* __restrict__ kf)
{
  int wid = threadIdx.x >> 6, l = threadIdx.x & 63;
  long row = (long)blockIdx.x*4 + wid;     // 0 .. B*MAXSEQ-1
  int b = (int)(row >> 11);
  int t = (int)(row & (MAXSEQ - 1));
  int sp = sp_ptr[0];
  int end = sp + S_;
  if(t < sp){
    const float* c = cache + row*QKHD;
    kf[row*QKHD + l]       = f2bf(c[l]);
    kf[row*QKHD + 64 + l]  = f2bf(c[64 + l]);
    kf[row*QKHD + 128 + l] = f2bf(c[128 + l]);
    return;
  }
  if(t >= end) return;
  int s = t - sp;
  const float* p = kvf + ((long)b*S_ + s)*NMERGE;
  float v0 = p[l] + kvb[l];
  float v1 = p[64 + l] + kvb[64 + l];
  float v2 = p[128 + l] + kvb[128 + l];
  float ss = v0*v0 + v1*v1 + v2*v2;
  #pragma unroll
  for(int off = 1; off < 64; off <<= 1) ss += __shfl_xor(ss, off);
  float scale = rsqrtf(ss / (float)QKHD + EPS_);
  float n0 = v0*scale*w[l], n1 = v1*scale*w[64 + l], n2 = v2*scale*w[128 + l];
  kf[row*QKHD + l]      = f2bf(n0);
  kf[row*QKHD + 64 + l] = f2bf(n1);
  int i = l >> 1;
  float cs = freqs[(s*32 + i)*2], sn = freqs[(s*32 + i)*2 + 1];
  float pv = __shfl_xor(n2, 1);
  float r = (l & 1) ? (pv*sn + n2*cs) : (n2*cs - pv*sn);
  kf[row*QKHD + 128 + l] = f2bf(r);
}

// ---------------- V transpose: KFULL[b][t][0:128] -> VT[b][d][t] ----------------
__global__ __launch_bounds__(256)
void k_vtrans(const short* __restrict__ kf, short* __restrict__ vt)
{
  __shared__ short T[32 * 132];
  const int b = blockIdx.y;
  const int t0 = blockIdx.x * 32;
  const int tid = threadIdx.x;
  #pragma unroll
  for(int i = 0; i < 4; i++){
    int c = tid + 256*i;
    int tr = c >> 5, dg = c & 31;
    short4v v = *reinterpret_cast<const short4v*>(&kf[((long)b*MAXSEQ + t0 + tr)*QKHD + dg*4]);
    *reinterpret_cast<short4v*>(&T[tr*132 + dg*4]) = v;
  }
  __syncthreads();
  #pragma unroll
  for(int i = 0; i < 4; i++){
    int c = tid + 256*i;
    int dr = c >> 3, tg = c & 7;
    short4v v;
    v.x = T[(tg*4 + 0)*132 + dr];
    v.y = T[(tg*4 + 1)*132 + dr];
    v.z = T[(tg*4 + 2)*132 + dr];
    v.w = T[(tg*4 + 3)*132 + dr];
    *reinterpret_cast<short4v*>(&vt[((long)b*128 + dr)*MAXSEQ + t0 + tg*4]) = v;
  }
}

// ---------------- flash attention v6 ----------------
// 1024 blocks (all resident: 4/CU via LDS 32.5KB), 4 waves x 16 q-rows.
// bid->tile mapping makes each CU's 4 residency rounds sum to exactly 66 iters:
// round g<2: tile = 31-8g-k (desc), g>=2: tile = 8*(3-g)+k (asc), k=(bid>>5)&7.
// K staged in LDS (swizzled, reg-prefetch); PV B-frags straight from global VT
// (L2-resident); P via per-wave LDS.
__global__ __launch_bounds__(256, 4)
void k_attn6(const short* __restrict__ qfull, const short* __restrict__ kf,
             const short* __restrict__ vt, const int* __restrict__ sp_ptr,
             short* __restrict__ oh)
{
  __shared__ short Ks[64 * 192];     // 24 KB, swizzled 16B chunks
  __shared__ short Ps[4][16 * 68];   // 8.5 KB
  const int tid = threadIdx.x;
  const int l = tid & 63, w = tid >> 6;
  const int lrow = l & 15, lhi = l >> 4;
  const int bid = blockIdx.x;
  const int g = bid >> 8, kk = (bid >> 5) & 7, hb = bid & 31;
  const int tile = (g < 2) ? (31 - 8*g - kk) : (8*(3 - g) + kk);
  const int h = hb & 15, b = hb >> 4;
  const int sp = sp_ptr[0];
  const long kbase = (long)b * MAXSEQ;
  const long vbase = (long)b * 128;
  const int q0 = tile * 64;

  short8 kreg[6];

  // hoist Q fragments
  short8 qa[6];
  {
    int s = q0 + w*16 + lrow;
    const short* qp = qfull + (((long)b*S_ + s)*NH + h)*QKHD + lhi*8;
    #pragma unroll
    for(int ks = 0; ks < 6; ks++) qa[ks] = *reinterpret_cast<const short8*>(qp + ks*32);
  }
  f32x4 o[8];
  #pragma unroll
  for(int df = 0; df < 8; df++) o[df] = (f32x4)0.0f;
  float mrun[4], lrun[4];
  #pragma unroll
  for(int i = 0; i < 4; i++){ mrun[i] = -1e30f; lrun[i] = 0.0f; }

  int hi = q0 + 64 + sp;
  int nt = (hi + 63) >> 6; if(nt > (MAXSEQ >> 6)) nt = MAXSEQ >> 6;

  // prologue: stage K tile 0
  {
    #pragma unroll
    for(int i = 0; i < 6; i++){
      int cid = tid + 256*i;  int r = cid/24, c = cid%24;
      kreg[i] = *reinterpret_cast<const short8*>(&kf[(kbase + r)*QKHD + c*8]);
    }
    #pragma unroll
    for(int i = 0; i < 6; i++){
      int cid = tid + 256*i;  int r = cid/24, c = cid%24;
      *reinterpret_cast<short8*>(&Ks[r*192 + (c ^ (r & 7))*8]) = kreg[i];
    }
  }
  __syncthreads();

  for(int t0 = 0; t0 < nt; t0++){
    const int T0 = t0 * 64;
    // issue K prefetch for t0+1 (lands during compute)
    if(t0 + 1 < nt){
      const int Tn = T0 + 64;
      #pragma unroll
      for(int i = 0; i < 6; i++){
        int cid = tid + 256*i;  int r = cid/24, c = cid%24;
        kreg[i] = *reinterpret_cast<const short8*>(&kf[(kbase + Tn + r)*QKHD + c*8]);
      }
    }
    // QK^T: 16q x 64t per wave
    f32x4 sc[4];
    #pragma unroll
    for(int tf = 0; tf < 4; tf++) sc[tf] = (f32x4)0.0f;
    #pragma unroll
    for(int ks = 0; ks < 6; ks++){
      #pragma unroll
      for(int tf = 0; tf < 4; tf++){
        int krow = tf*16 + lrow;
        int cs = (ks*4 + lhi) ^ (lrow & 7);
        short8 bfr = *reinterpret_cast<const short8*>(&Ks[krow*192 + cs*8]);
        sc[tf] = __builtin_amdgcn_mfma_f32_16x16x32_bf16(qa[ks], bfr, sc[tf], 0, 0, 0);
      }
    }
    // online softmax with defer-max (THR=8)
    const bool needmask = (T0 + 63 > q0 + w*16 + sp);
    #pragma unroll
    for(int rr = 0; rr < 4; rr++){
      int q = q0 + w*16 + lhi*4 + rr;
      float s0 = sc[0][rr]*SCALE_, s1 = sc[1][rr]*SCALE_;
      float s2 = sc[2][rr]*SCALE_, s3 = sc[3][rr]*SCALE_;
      if(needmask){
        int t = T0 + lrow;
        if(t      > q + sp) s0 = -1e30f;
        if(t + 16 > q + sp) s1 = -1e30f;
        if(t + 32 > q + sp) s2 = -1e30f;
        if(t + 48 > q + sp) s3 = -1e30f;
      }
      float mx = fmaxf(fmaxf(s0, s1), fmaxf(s2, s3));
      #pragma unroll
      for(int off = 1; off < 16; off <<= 1) mx = fmaxf(mx, __shfl_xor(mx, off));
      if(mx > mrun[rr] + 8.0f){
        float corr = __expf(mrun[rr] - mx);
        lrun[rr] *= corr;
        #pragma unroll
        for(int df = 0; df < 8; df++) o[df][rr] *= corr;
        mrun[rr] = mx;
      }
      float p0 = __expf(s0 - mrun[rr]), p1 = __expf(s1 - mrun[rr]);
      float p2 = __expf(s2 - mrun[rr]), p3 = __expf(s3 - mrun[rr]);
      float psum = (p0 + p1) + (p2 + p3);
      #pragma unroll
      for(int off = 1; off < 16; off <<= 1) psum += __shfl_xor(psum, off);
      lrun[rr] += psum;
      int prow = lhi*4 + rr;
      Ps[w][prow*68 + lrow]      = f2bf(p0);
      Ps[w][prow*68 + 16 + lrow] = f2bf(p1);
      Ps[w][prow*68 + 32 + lrow] = f2bf(p2);
      Ps[w][prow*68 + 48 + lrow] = f2bf(p3);
    }
    // PV: A from per-wave Ps, B straight from global VT (L2-resident)
    short8 pa[2];
    #pragma unroll
    for(int kc = 0; kc < 2; kc++)
      pa[kc] = *reinterpret_cast<const short8*>(&Ps[w][lrow*68 + kc*32 + lhi*8]);
    #pragma unroll
    for(int df = 0; df < 8; df++){
      #pragma unroll
      for(int kc = 0; kc < 2; kc++){
        short8 vfr = *reinterpret_cast<const short8*>(
            &vt[(vbase + df*16 + lrow)*MAXSEQ + T0 + kc*32 + lhi*8]);
        o[df] = __builtin_amdgcn_mfma_f32_16x16x32_bf16(pa[kc], vfr, o[df], 0, 0, 0);
      }
    }
    __syncthreads();
    // write prefetched K into LDS
    if(t0 + 1 < nt){
      #pragma unroll
      for(int i = 0; i < 6; i++){
        int cid = tid + 256*i;  int r = cid/24, c = cid%24;
        *reinterpret_cast<short8*>(&Ks[r*192 + (c ^ (r & 7))*8]) = kreg[i];
      }
      __syncthreads();
    }
  }
  // epilogue
  #pragma unroll
  for(int rr = 0; rr < 4; rr++){
    int s = q0 + w*16 + lhi*4 + rr;
    float inv = 1.0f / lrun[rr];
    #pragma unroll
    for(int df = 0; df < 8; df++)
      oh[(((long)b*S_ + s)*NH + h)*128 + df*16 + lrow] = f2bf(o[df][rr] * inv);
  }
}

// ---------------- head-sum (vectorized): (B*S,16,128) -> (B*S,128) ------------
__global__ __launch_bounds__(256)
void k_redheads(const short* __restrict__ ohp, short* __restrict__ hs){
  long idx = (long)blockIdx.x*256 + threadIdx.x;  // < 4096*32
  long row = idx >> 5; int d4 = (int)(idx & 31);
  float a0 = 0, a1 = 0, a2 = 0, a3 = 0;
  #pragma unroll
  for(int h = 0; h < NH; h++){
    short4v v = *reinterpret_cast<const short4v*>(&ohp[(row*NH + h)*128 + d4*4]);
    a0 += bf2f(v.x); a1 += bf2f(v.y); a2 += bf2f(v.z); a3 += bf2f(v.w);
  }
  short4v o; o.x = f2bf(a0); o.y = f2bf(a1); o.z = f2bf(a2); o.w = f2bf(a3);
  *reinterpret_cast<short4v*>(&hs[row*128 + d4*4]) = o;
}

// ---------------- ws layout (bytes) ----------------
static constexpr size_t OFF_X16   = 0;                    // bf16 x        16,777,216
static constexpr size_t OFF_WQAKV = 16777216;             // bf16 [wqa;wkva] 7,077,888
static constexpr size_t OFF_WQB   = 23855104;             // bf16 wqb       9,437,184
static constexpr size_t OFF_WUK   = 33292288;             // bf16 wuk          32,768
static constexpr size_t OFF_WUV   = 33325056;             // bf16 wuv         524,288
static constexpr size_t OFF_QNORM = 33849344;             // bf16 qnorm    12,582,912
static constexpr size_t OFF_QFULL = 46432256;             // bf16 qfull    25,165,824
static constexpr size_t OFF_KFULL = 71598080;             // bf16 k cache   1,572,864
static constexpr size_t OFF_HSUM  = 73170944;             // bf16 head sum  1,048,576
static constexpr size_t OFF_SCR   = 74219520;             // overlay region
static constexpr size_t OFF_QAKV  = OFF_SCR;              // f32 merged out 28,311,552 (ph1)
static constexpr size_t OFF_Q16   = OFF_SCR;              // bf16 q (ph2, QAKV dead)
static constexpr size_t OFF_QN    = OFF_SCR + 25165824;   // bf16 q_nope (ph2)
static constexpr size_t OFF_OH    = OFF_SCR;              // bf16 per-head O (ph3)
static constexpr size_t OFF_VT    = OFF_SCR + 41943040;   // bf16 V^T 1,048,576

extern "C" void kernel_launch(void* const* d_in, const int* in_sizes, int n_in,
                              void* d_out, int out_size, void* d_ws, size_t ws_size,
                              hipStream_t stream)
{
  const float* x      = (const float*)d_in[0];
  const int*   sp     = (const int*)  d_in[1];
  const float* freqs  = (const float*)d_in[2];
  const float* cache  = (const float*)d_in[4];
  const float* wqa_w  = (const float*)d_in[5];
  const float* wqa_b  = (const float*)d_in[6];
  const float* wqb_w  = (const float*)d_in[7];
  const float* wqb_b  = (const float*)d_in[8];
  const float* qnw    = (const float*)d_in[9];
  const float* wkva_w = (const float*)d_in[10];
  const float* wkva_b = (const float*)d_in[11];
  const float* knw    = (const float*)d_in[12];
  const float* wuk_w  = (const float*)d_in[13];
  const float* wuk_b  = (const float*)d_in[14];
  const float* wuv_w  = (const float*)d_in[15];
  const float* wuv_b  = (const float*)d_in[16];

  char* ws = (char*)d_ws;
  short* X16   = (short*)(ws + OFF_X16);
  short* WQAKV = (short*)(ws + OFF_WQAKV);
  short* WQB16 = (short*)(ws + OFF_WQB);
  short* WUK16 = (short*)(ws + OFF_WUK);
  short* WUV16 = (short*)(ws + OFF_WUV);
  short* QNORM = (short*)(ws + OFF_QNORM);
  short* QFULL = (short*)(ws + OFF_QFULL);
  short* KFULL = (short*)(ws + OFF_KFULL);
  short* HSUM  = (short*)(ws + OFF_HSUM);
  float* QAKV  = (float*)(ws + OFF_QAKV);
  short* Q16   = (short*)(ws + OFF_Q16);
  short* QN16  = (short*)(ws + OFF_QN);
  short* OH16  = (short*)(ws + OFF_OH);
  short* VT16  = (short*)(ws + OFF_VT);

  auto cvt = [&](const float* src, short* dst, long n){
    long blocks = (n/4 + 255) / 256; if(blocks > 2048) blocks = 2048;
    k_f2b<<<(int)blocks, 256, 0, stream>>>(src, dst, n);
  };
  cvt(x,      X16,   (long)B_*S_*2048);
  cvt(wqa_w,  WQAKV, (long)QRANK*2048);
  cvt(wkva_w, WQAKV + (long)QRANK*2048, (long)QKHD*2048);
  cvt(wqb_w,  WQB16, (long)NH*QKHD*QRANK);
  cvt(wuk_w,  WUK16, (long)NOPE_*NOPE_);
  cvt(wuv_w,  WUV16, (long)2048*NOPE_);

  // merged: [qa | kv] = x @ [wqa; wkva]^T   (f32, no bias -> added downstream)
  k_gemm97<64,false><<<dim3(32,27), 256, 0, stream>>>(X16, WQAKV, nullptr, 0.0f, QAKV, 4096, NMERGE, 2048, NMERGE);
  // rms norm (+wqa_b) -> bf16
  k_rms_q<<<4096, 256, 0, stream>>>(QAKV, wqa_b, qnw, QNORM);
  // kv: +wkva_b, rms, rope, cache merge -> k_full bf16
  k_kvproc<<<1024, 256, 0, stream>>>(QAKV + QRANK, wkva_b, knw, freqs, cache, sp, KFULL);
  // q = qnorm @ wqb^T + b   (bf16)
  k_gemm97<128,true><<<dim3(32,24), 256, 0, stream>>>(QNORM, WQB16, wqb_b, 1.0f, Q16, 4096, NH*QKHD, QRANK, NH*QKHD);
  // split nope / rope pe (vectorized)
  k_qassemble<<<12288, 256, 0, stream>>>(Q16, freqs, QN16, QFULL);
  // q_abs = q_nope @ wuk^T + b  -> qfull[...,:128]
  k_gemm97<128,true><<<dim3(512,1), 256, 0, stream>>>(QN16, WUK16, wuk_b, 1.0f, QFULL, 65536, 128, 128, QKHD);
  // V transpose -> VT[b][d][t]
  k_vtrans<<<dim3(64,2), 256, 0, stream>>>(KFULL, VT16);
  // flash attention v6 (all-resident, CU-balanced, PV from global VT)
  k_attn6<<<1024, 256, 0, stream>>>(QFULL, KFULL, VT16, sp, OH16);
  // head sum (vectorized)
  k_redheads<<<512, 256, 0, stream>>>(OH16, HSUM);
  // out = hsum @ wuv^T + 16*b  (f32 -> d_out)
  k_gemm97<64,false><<<dim3(32,32), 256, 0, stream>>>(HSUM, WUV16, wuv_b, 16.0f, (float*)d_out, 4096, 2048, NOPE_, 2048);
}

// Round 7
// 471.593 us; speedup vs baseline: 1.2288x; 1.2288x over previous
//
#include <hip/hip_runtime.h>
#include <hip/hip_bf16.h>
#include <stdint.h>

// ---------------- problem constants ----------------
#define NH     16
#define QRANK  1536
#define NOPE_  128
#define QKHD   192
#define NMERGE 1728   // QRANK + QKHD
#define B_     2
#define S_     2048
#define MAXSEQ 2048
#define EPS_   1e-6f
#define SCALE_ 0.07216878364870322f  // 192^-0.5

typedef __attribute__((ext_vector_type(4))) float f32x4;
typedef __attribute__((ext_vector_type(8))) short short8;
typedef __attribute__((ext_vector_type(4))) short short4v;

__device__ inline short f2bf(float f){
  uint32_t u = __builtin_bit_cast(uint32_t, f);
  uint32_t r = (u + 0x7FFFu + ((u >> 16) & 1u)) >> 16;
  return (short)(uint16_t)r;
}
__device__ inline float bf2f(short s){
  uint32_t u = ((uint32_t)(uint16_t)s) << 16;
  return __builtin_bit_cast(float, u);
}
__device__ inline void gload16(const short* g, short* l){
  __builtin_amdgcn_global_load_lds((const __attribute__((address_space(1))) void*)g,
                                   (__attribute__((address_space(3))) void*)l, 16, 0, 0);
}

// ---------------- fused f32->bf16 convert, 5 jobs in one launch ----------------
__global__ void k_cvt5(const float* s0, short* d0, long n0,
                       const float* s1, short* d1, long n1,
                       const float* s2, short* d2, long n2,
                       const float* s3, short* d3, long n3,
                       const float* s4, short* d4, long n4)
{
  const float* src; short* dst; long n;
  switch(blockIdx.y){
    case 0: src = s0; dst = d0; n = n0; break;
    case 1: src = s1; dst = d1; n = n1; break;
    case 2: src = s2; dst = d2; n = n2; break;
    case 3: src = s3; dst = d3; n = n3; break;
    default: src = s4; dst = d4; n = n4; break;
  }
  long i = ((long)blockIdx.x * blockDim.x + threadIdx.x) * 4;
  long stride = (long)gridDim.x * blockDim.x * 4;
  for(; i < n; i += stride){
    float4 v = *reinterpret_cast<const float4*>(src + i);
    short4v o;
    o.x = f2bf(v.x); o.y = f2bf(v.y); o.z = f2bf(v.z); o.w = f2bf(v.w);
    *reinterpret_cast<short4v*>(dst + i) = o;
  }
}

// ---------------- wuk transpose+convert: WUKT[e][d] = bf16(wuk[d][e]) ----------
__global__ __launch_bounds__(256)
void k_wukT(const float* __restrict__ wuk, short* __restrict__ wukt){
  int idx = blockIdx.x*256 + threadIdx.x;   // < 16384
  int e = idx >> 7, d = idx & 127;
  wukt[e*128 + d] = f2bf(wuk[d*128 + e]);
}

// ---------------- m97 GEMM + XCD swizzle: C = A[M][K](lda)@B[N][K]^T + bias ----
template<int BN, bool OUT_BF16>
__global__ __launch_bounds__(256)
void k_gemm97(const short* __restrict__ A, const short* __restrict__ Bm,
              const float* __restrict__ bias, float biasScale,
              void* __restrict__ Cp, int lda, int K, int ldc)
{
  constexpr int WN = BN / 2, FN = WN / 16;
  __shared__ short As[128 * 32];
  __shared__ short Bs[BN * 32];
  const int tid = threadIdx.x;
  const int l = tid & 63, w = tid >> 6;
  const int wr = w >> 1, wc = w & 1;
  // XCD-aware by-major swizzle: each XCD keeps few A-tiles L2-resident
  int nx = gridDim.x, ny = gridDim.y;
  int lin = (int)blockIdx.x + nx*(int)blockIdx.y;
  int nwg = nx*ny;
  if((nwg & 7) == 0){ int ch = nwg >> 3; lin = (lin & 7)*ch + (lin >> 3); }
  const long m0 = (long)(lin / ny) * 128;
  const long n0 = (long)(lin % ny) * BN;
  const int lrow = l & 15, lk8 = (l >> 4) * 8;

  int ciA0 = (w*2 + 0)*64 + l, ciA1 = (w*2 + 1)*64 + l;
  const short* a0 = &A[(m0 + (ciA0 >> 2))*(long)lda + (ciA0 & 3)*8];
  const short* a1 = &A[(m0 + (ciA1 >> 2))*(long)lda + (ciA1 & 3)*8];
  short* lA0 = &As[(w*2 + 0)*512];
  short* lA1 = &As[(w*2 + 1)*512];

  const short* b0; const short* b1 = nullptr;
  short* lB0; short* lB1 = nullptr;
  if constexpr (BN == 128){
    int ciB0 = (w*2 + 0)*64 + l, ciB1 = (w*2 + 1)*64 + l;
    b0 = &Bm[(n0 + (ciB0 >> 2))*(long)K + (ciB0 & 3)*8];
    b1 = &Bm[(n0 + (ciB1 >> 2))*(long)K + (ciB1 & 3)*8];
    lB0 = &Bs[(w*2 + 0)*512];
    lB1 = &Bs[(w*2 + 1)*512];
  } else {
    int ciB = w*64 + l;
    b0 = &Bm[(n0 + (ciB >> 2))*(long)K + (ciB & 3)*8];
    lB0 = &Bs[w*512];
  }

  f32x4 acc[4][FN];
  #pragma unroll
  for(int m = 0; m < 4; m++)
    #pragma unroll
    for(int n = 0; n < FN; n++) acc[m][n] = (f32x4)0.0f;

  for(int kt = 0; kt < K; kt += 32){
    gload16(a0 + kt, lA0);
    gload16(a1 + kt, lA1);
    gload16(b0 + kt, lB0);
    if constexpr (BN == 128) gload16(b1 + kt, lB1);
    __syncthreads();
    short8 af[4], bfv[FN];
    #pragma unroll
    for(int m = 0; m < 4; m++)
      af[m] = *reinterpret_cast<const short8*>(&As[(wr*64 + m*16 + lrow)*32 + lk8]);
    #pragma unroll
    for(int n = 0; n < FN; n++)
      bfv[n] = *reinterpret_cast<const short8*>(&Bs[(wc*WN + n*16 + lrow)*32 + lk8]);
    #pragma unroll
    for(int m = 0; m < 4; m++)
      #pragma unroll
      for(int n = 0; n < FN; n++)
        acc[m][n] = __builtin_amdgcn_mfma_f32_16x16x32_bf16(af[m], bfv[n], acc[m][n], 0, 0, 0);
    __syncthreads();
  }
  #pragma unroll
  for(int m = 0; m < 4; m++){
    int row_l = wr*64 + m*16 + (l >> 4)*4;
    #pragma unroll
    for(int n = 0; n < FN; n++){
      int col = (int)n0 + wc*WN + n*16 + lrow;
      float bv = bias ? bias[col]*biasScale : 0.0f;
      #pragma unroll
      for(int r = 0; r < 4; r++){
        long row = m0 + row_l + r;
        float v = acc[m][n][r] + bv;
        if constexpr (OUT_BF16) ((short*)Cp)[row*(long)ldc + col] = f2bf(v);
        else                    ((float*)Cp)[row*(long)ldc + col] = v;
      }
    }
  }
}

// ---------------- RMS norm over 1536 (rows stride 1728), + input bias ---------
__global__ __launch_bounds__(256)
void k_rms_q(const float* __restrict__ in, const float* __restrict__ bias,
             const float* __restrict__ w, short* __restrict__ out)
{
  const int row = blockIdx.x;
  const int tid = threadIdx.x;
  const float* p = in + (long)row * NMERGE;
  float v[6]; float ss = 0.0f;
  #pragma unroll
  for(int i = 0; i < 6; i++){
    int c = tid + 256*i;
    v[i] = p[c] + bias[c];
    ss += v[i]*v[i];
  }
  #pragma unroll
  for(int off = 1; off < 64; off <<= 1) ss += __shfl_xor(ss, off);
  __shared__ float red[4];
  if((tid & 63) == 0) red[tid >> 6] = ss;
  __syncthreads();
  ss = red[0] + red[1] + red[2] + red[3];
  float scale = rsqrtf(ss / (float)QRANK + EPS_);
  #pragma unroll
  for(int i = 0; i < 6; i++){
    int c = tid + 256*i;
    out[(long)row*QRANK + c] = f2bf(v[i] * scale * w[c]);
  }
}

// ---------------- q rope in-place on qfull[...,128:192] ----------------
__global__ __launch_bounds__(256)
void k_qrope(short* __restrict__ qfull, const float* __restrict__ freqs){
  long idx = (long)blockIdx.x*256 + threadIdx.x;   // < 65536*16
  long row = idx >> 4; int c = (int)(idx & 15);    // row = bs*16+h
  int s = (int)((row >> 4) & (S_ - 1));
  short* p = &qfull[row*QKHD + 128 + c*4];
  short4v v = *reinterpret_cast<const short4v*>(p);
  float a0 = bf2f(v.x), b0 = bf2f(v.y), a1 = bf2f(v.z), b1 = bf2f(v.w);
  int p0 = s*32 + c*2, p1 = p0 + 1;
  float cs0 = freqs[p0*2], sn0 = freqs[p0*2 + 1];
  float cs1 = freqs[p1*2], sn1 = freqs[p1*2 + 1];
  short4v o;
  o.x = f2bf(a0*cs0 - b0*sn0); o.y = f2bf(a0*sn0 + b0*cs0);
  o.z = f2bf(a1*cs1 - b1*sn1); o.w = f2bf(a1*sn1 + b1*cs1);
  *reinterpret_cast<short4v*>(p) = o;
}

// ---------------- kv: +bias, RMS(192), rope(last 64), cache merge --------------
__global__ __launch_bounds__(256)
void k_kvproc(const float* __restrict__ kvf, const float* __restrict__ kvb,
              const float* __restrict__ w, const float* __restrict__ freqs,
              const float* __restrict__ cache, const int* __restrict__ sp_ptr,
              short* __restrict__ kf)
{
  int wid = threadIdx.x >> 6, l = threadIdx.x & 63;
  long row = (long)blockIdx.x*4 + wid;     // 0 .. B*MAXSEQ-1
  int b = (int)(row >> 11);
  int t = (int)(row & (MAXSEQ - 1));
  int sp = sp_ptr[0];
  int end = sp + S_;
  if(t < sp){
    const float* c = cache + row*QKHD;
    kf[row*QKHD + l]       = f2bf(c[l]);
    kf[row*QKHD + 64 + l]  = f2bf(c[64 + l]);
    kf[row*QKHD + 128 + l] = f2bf(c[128 + l]);
    return;
  }
  if(t >= end) return;
  int s = t - sp;
  const float* p = kvf + ((long)b*S_ + s)*NMERGE;
  float v0 = p[l] + kvb[l];
  float v1 = p[64 + l] + kvb[64 + l];
  float v2 = p[128 + l] + kvb[128 + l];
  float ss = v0*v0 + v1*v1 + v2*v2;
  #pragma unroll
  for(int off = 1; off < 64; off <<= 1) ss += __shfl_xor(ss, off);
  float scale = rsqrtf(ss / (float)QKHD + EPS_);
  float n0 = v0*scale*w[l], n1 = v1*scale*w[64 + l], n2 = v2*scale*w[128 + l];
  kf[row*QKHD + l]      = f2bf(n0);
  kf[row*QKHD + 64 + l] = f2bf(n1);
  int i = l >> 1;
  float cs = freqs[(s*32 + i)*2], sn = freqs[(s*32 + i)*2 + 1];
  float pv = __shfl_xor(n2, 1);
  float r = (l & 1) ? (pv*sn + n2*cs) : (n2*cs - pv*sn);
  kf[row*QKHD + 128 + l] = f2bf(r);
}

// ---- KQ finish: copy rope part KFULL->KQ, kb[t] = dot(wuk_b, k_nope[t]) ------
__global__ __launch_bounds__(256)
void k_kqfin(const short* __restrict__ kf, const float* __restrict__ wukb,
             short* __restrict__ kq, float* __restrict__ kb)
{
  int wid = threadIdx.x >> 6, l = threadIdx.x & 63;
  long row = (long)blockIdx.x*4 + wid;     // 0 .. 4095
  // copy rope 64 shorts
  kq[row*QKHD + 128 + l] = kf[row*QKHD + 128 + l];
  // kb dot over nope 128
  float acc = bf2f(kf[row*QKHD + 2*l]) * wukb[2*l]
            + bf2f(kf[row*QKHD + 2*l + 1]) * wukb[2*l + 1];
  #pragma unroll
  for(int off = 1; off < 64; off <<= 1) acc += __shfl_xor(acc, off);
  if(l == 0) kb[row] = acc;
}

// ---------------- V transpose: KFULL[b][t][0:128] -> VT[b][d][t] ----------------
__global__ __launch_bounds__(256)
void k_vtrans(const short* __restrict__ kf, short* __restrict__ vt)
{
  __shared__ short T[32 * 132];
  const int b = blockIdx.y;
  const int t0 = blockIdx.x * 32;
  const int tid = threadIdx.x;
  #pragma unroll
  for(int i = 0; i < 4; i++){
    int c = tid + 256*i;
    int tr = c >> 5, dg = c & 31;
    short4v v = *reinterpret_cast<const short4v*>(&kf[((long)b*MAXSEQ + t0 + tr)*QKHD + dg*4]);
    *reinterpret_cast<short4v*>(&T[tr*132 + dg*4]) = v;
  }
  __syncthreads();
  #pragma unroll
  for(int i = 0; i < 4; i++){
    int c = tid + 256*i;
    int dr = c >> 3, tg = c & 7;
    short4v v;
    v.x = T[(tg*4 + 0)*132 + dr];
    v.y = T[(tg*4 + 1)*132 + dr];
    v.z = T[(tg*4 + 2)*132 + dr];
    v.w = T[(tg*4 + 3)*132 + dr];
    *reinterpret_cast<short4v*>(&vt[((long)b*128 + dr)*MAXSEQ + t0 + tg*4]) = v;
  }
}

// ---------------- flash attention v7 (= proven v5 + KQ/kb inputs) ----------------
// grid (16,16,2), 4 waves x 16 q-rows; block does tiles (p, 31-p) = 33 kv-iters.
// QK reads KQ = [k_abs | k_rope]; scores += kb[t] (wuk_b term); V from LDS Vs.
__global__ __launch_bounds__(256, 3)
void k_attn7(const short* __restrict__ qfull, const short* __restrict__ kq,
             const short* __restrict__ vtg, const float* __restrict__ kb,
             const int* __restrict__ sp_ptr, short* __restrict__ oh)
{
  __shared__ short Ks[64 * 192];     // swizzled 16B chunks
  __shared__ short Vs[128 * 64];
  __shared__ short Ps[4][16 * 68];
  const int tid = threadIdx.x;
  const int l = tid & 63, w = tid >> 6;
  const int lrow = l & 15, lhi = l >> 4;
  const int h = blockIdx.y, b = blockIdx.z;
  const int sp = sp_ptr[0];
  const long kbase = (long)b * MAXSEQ;
  const long vbase = (long)b * 128;

  short8 kreg[6], vreg[4];

  #pragma unroll 1
  for(int part = 0; part < 2; part++){
    const int tile = part ? (31 - (int)blockIdx.x) : (int)blockIdx.x;
    const int q0 = tile * 64;

    short8 qa[6];
    {
      int s = q0 + w*16 + lrow;
      const short* qp = qfull + (((long)b*S_ + s)*NH + h)*QKHD + lhi*8;
      #pragma unroll
      for(int ks = 0; ks < 6; ks++) qa[ks] = *reinterpret_cast<const short8*>(qp + ks*32);
    }
    f32x4 o[8];
    #pragma unroll
    for(int df = 0; df < 8; df++) o[df] = (f32x4)0.0f;
    float mrun[4], lrun[4];
    #pragma unroll
    for(int i = 0; i < 4; i++){ mrun[i] = -1e30f; lrun[i] = 0.0f; }

    int hi = q0 + 64 + sp;
    int nt = (hi + 63) >> 6; if(nt > (MAXSEQ >> 6)) nt = MAXSEQ >> 6;

    // prologue: fetch + write tile 0
    {
      #pragma unroll
      for(int i = 0; i < 6; i++){
        int cid = tid + 256*i;  int r = cid/24, c = cid%24;
        kreg[i] = *reinterpret_cast<const short8*>(&kq[(kbase + r)*QKHD + c*8]);
      }
      #pragma unroll
      for(int i = 0; i < 4; i++){
        int cid = tid + 256*i;  int r = cid >> 3, c = cid & 7;
        vreg[i] = *reinterpret_cast<const short8*>(&vtg[(vbase + r)*MAXSEQ + c*8]);
      }
      #pragma unroll
      for(int i = 0; i < 6; i++){
        int cid = tid + 256*i;  int r = cid/24, c = cid%24;
        *reinterpret_cast<short8*>(&Ks[r*192 + (c ^ (r & 7))*8]) = kreg[i];
      }
      #pragma unroll
      for(int i = 0; i < 4; i++){
        int cid = tid + 256*i;  int r = cid >> 3, c = cid & 7;
        *reinterpret_cast<short8*>(&Vs[r*64 + (c ^ (r & 7))*8]) = vreg[i];
      }
    }
    __syncthreads();

    for(int t0 = 0; t0 < nt; t0++){
      const int T0 = t0 * 64;
      if(t0 + 1 < nt){
        const int Tn = T0 + 64;
        #pragma unroll
        for(int i = 0; i < 6; i++){
          int cid = tid + 256*i;  int r = cid/24, c = cid%24;
          kreg[i] = *reinterpret_cast<const short8*>(&kq[(kbase + Tn + r)*QKHD + c*8]);
        }
        #pragma unroll
        for(int i = 0; i < 4; i++){
          int cid = tid + 256*i;  int r = cid >> 3, c = cid & 7;
          vreg[i] = *reinterpret_cast<const short8*>(&vtg[(vbase + r)*MAXSEQ + Tn + c*8]);
        }
      }
      // kb terms for this tile (t = T0 + lrow + 16*j), L2-resident tiny array
      float kb0 = kb[kbase + T0 + lrow];
      float kb1 = kb[kbase + T0 + 16 + lrow];
      float kb2 = kb[kbase + T0 + 32 + lrow];
      float kb3 = kb[kbase + T0 + 48 + lrow];
      // QK^T
      f32x4 sc[4];
      #pragma unroll
      for(int tf = 0; tf < 4; tf++) sc[tf] = (f32x4)0.0f;
      #pragma unroll
      for(int ks = 0; ks < 6; ks++){
        #pragma unroll
        for(int tf = 0; tf < 4; tf++){
          int krow = tf*16 + lrow;
          int cs = (ks*4 + lhi) ^ (lrow & 7);
          short8 bfr = *reinterpret_cast<const short8*>(&Ks[krow*192 + cs*8]);
          sc[tf] = __builtin_amdgcn_mfma_f32_16x16x32_bf16(qa[ks], bfr, sc[tf], 0, 0, 0);
        }
      }
      // online softmax with defer-max (THR=8)
      const bool needmask = (T0 + 63 > q0 + w*16 + sp);
      #pragma unroll
      for(int rr = 0; rr < 4; rr++){
        int q = q0 + w*16 + lhi*4 + rr;
        float s0 = (sc[0][rr] + kb0)*SCALE_, s1 = (sc[1][rr] + kb1)*SCALE_;
        float s2 = (sc[2][rr] + kb2)*SCALE_, s3 = (sc[3][rr] + kb3)*SCALE_;
        if(needmask){
          int t = T0 + lrow;
          if(t      > q + sp) s0 = -1e30f;
          if(t + 16 > q + sp) s1 = -1e30f;
          if(t + 32 > q + sp) s2 = -1e30f;
          if(t + 48 > q + sp) s3 = -1e30f;
        }
        float mx = fmaxf(fmaxf(s0, s1), fmaxf(s2, s3));
        #pragma unroll
        for(int off = 1; off < 16; off <<= 1) mx = fmaxf(mx, __shfl_xor(mx, off));
        if(mx > mrun[rr] + 8.0f){
          float corr = __expf(mrun[rr] - mx);
          lrun[rr] *= corr;
          #pragma unroll
          for(int df = 0; df < 8; df++) o[df][rr] *= corr;
          mrun[rr] = mx;
        }
        float p0 = __expf(s0 - mrun[rr]), p1 = __expf(s1 - mrun[rr]);
        float p2 = __expf(s2 - mrun[rr]), p3 = __expf(s3 - mrun[rr]);
        float psum = (p0 + p1) + (p2 + p3);
        #pragma unroll
        for(int off = 1; off < 16; off <<= 1) psum += __shfl_xor(psum, off);
        lrun[rr] += psum;
        int prow = lhi*4 + rr;
        Ps[w][prow*68 + lrow]      = f2bf(p0);
        Ps[w][prow*68 + 16 + lrow] = f2bf(p1);
        Ps[w][prow*68 + 32 + lrow] = f2bf(p2);
        Ps[w][prow*68 + 48 + lrow] = f2bf(p3);
      }
      // PV from LDS Vs
      short8 pa[2];
      #pragma unroll
      for(int kc = 0; kc < 2; kc++)
        pa[kc] = *reinterpret_cast<const short8*>(&Ps[w][lrow*68 + kc*32 + lhi*8]);
      #pragma unroll
      for(int df = 0; df < 8; df++){
        #pragma unroll
        for(int kc = 0; kc < 2; kc++){
          int vrow = df*16 + lrow;
          int cs = (kc*4 + lhi) ^ (lrow & 7);
          short8 vfr = *reinterpret_cast<const short8*>(&Vs[vrow*64 + cs*8]);
          o[df] = __builtin_amdgcn_mfma_f32_16x16x32_bf16(pa[kc], vfr, o[df], 0, 0, 0);
        }
      }
      __syncthreads();
      if(t0 + 1 < nt){
        #pragma unroll
        for(int i = 0; i < 6; i++){
          int cid = tid + 256*i;  int r = cid/24, c = cid%24;
          *reinterpret_cast<short8*>(&Ks[r*192 + (c ^ (r & 7))*8]) = kreg[i];
        }
        #pragma unroll
        for(int i = 0; i < 4; i++){
          int cid = tid + 256*i;  int r = cid >> 3, c = cid & 7;
          *reinterpret_cast<short8*>(&Vs[r*64 + (c ^ (r & 7))*8]) = vreg[i];
        }
        __syncthreads();
      }
    }
    // epilogue
    #pragma unroll
    for(int rr = 0; rr < 4; rr++){
      int s = q0 + w*16 + lhi*4 + rr;
      float inv = 1.0f / lrun[rr];
      #pragma unroll
      for(int df = 0; df < 8; df++)
        oh[(((long)b*S_ + s)*NH + h)*128 + df*16 + lrow] = f2bf(o[df][rr] * inv);
    }
  }
}

// ---------------- head-sum (vectorized): (B*S,16,128) -> (B*S,128) ------------
__global__ __launch_bounds__(256)
void k_redheads(const short* __restrict__ ohp, short* __restrict__ hs){
  long idx = (long)blockIdx.x*256 + threadIdx.x;  // < 4096*32
  long row = idx >> 5; int d4 = (int)(idx & 31);
  float a0 = 0, a1 = 0, a2 = 0, a3 = 0;
  #pragma unroll
  for(int h = 0; h < NH; h++){
    short4v v = *reinterpret_cast<const short4v*>(&ohp[(row*NH + h)*128 + d4*4]);
    a0 += bf2f(v.x); a1 += bf2f(v.y); a2 += bf2f(v.z); a3 += bf2f(v.w);
  }
  short4v o; o.x = f2bf(a0); o.y = f2bf(a1); o.z = f2bf(a2); o.w = f2bf(a3);
  *reinterpret_cast<short4v*>(&hs[row*128 + d4*4]) = o;
}

// ---------------- ws layout (bytes) ----------------
static constexpr size_t OFF_X16   = 0;                    // 16,777,216
static constexpr size_t OFF_WQAKV = 16777216;             //  7,077,888
static constexpr size_t OFF_WQB   = 23855104;             //  9,437,184
static constexpr size_t OFF_WUKT  = 33292288;             //     32,768
static constexpr size_t OFF_WUV   = 33325056;             //    524,288
static constexpr size_t OFF_QNORM = 33849344;             // 12,582,912
static constexpr size_t OFF_QFULL = 46432256;             // 25,165,824
static constexpr size_t OFF_KFULL = 71598080;             //  1,572,864
static constexpr size_t OFF_KQ    = 73170944;             //  1,572,864
static constexpr size_t OFF_KB    = 74743808;             //     16,384
static constexpr size_t OFF_VT    = 74760192;             //  1,048,576
static constexpr size_t OFF_HSUM  = 75808768;             //  1,048,576
static constexpr size_t OFF_SCR   = 76857344;             // overlay
static constexpr size_t OFF_QAKV  = OFF_SCR;              // f32 28,311,552 (ph1)
static constexpr size_t OFF_OH    = OFF_SCR;              // bf16 16.8MB (ph3, QAKV dead)

extern "C" void kernel_launch(void* const* d_in, const int* in_sizes, int n_in,
                              void* d_out, int out_size, void* d_ws, size_t ws_size,
                              hipStream_t stream)
{
  const float* x      = (const float*)d_in[0];
  const int*   sp     = (const int*)  d_in[1];
  const float* freqs  = (const float*)d_in[2];
  const float* cache  = (const float*)d_in[4];
  const float* wqa_w  = (const float*)d_in[5];
  const float* wqa_b  = (const float*)d_in[6];
  const float* wqb_w  = (const float*)d_in[7];
  const float* wqb_b  = (const float*)d_in[8];
  const float* qnw    = (const float*)d_in[9];
  const float* wkva_w = (const float*)d_in[10];
  const float* wkva_b = (const float*)d_in[11];
  const float* knw    = (const float*)d_in[12];
  const float* wuk_w  = (const float*)d_in[13];
  const float* wuk_b  = (const float*)d_in[14];
  const float* wuv_w  = (const float*)d_in[15];
  const float* wuv_b  = (const float*)d_in[16];

  char* ws = (char*)d_ws;
  short* X16   = (short*)(ws + OFF_X16);
  short* WQAKV = (short*)(ws + OFF_WQAKV);
  short* WQB16 = (short*)(ws + OFF_WQB);
  short* WUKT  = (short*)(ws + OFF_WUKT);
  short* WUV16 = (short*)(ws + OFF_WUV);
  short* QNORM = (short*)(ws + OFF_QNORM);
  short* QFULL = (short*)(ws + OFF_QFULL);
  short* KFULL = (short*)(ws + OFF_KFULL);
  short* KQ    = (short*)(ws + OFF_KQ);
  float* KB    = (float*)(ws + OFF_KB);
  short* VT16  = (short*)(ws + OFF_VT);
  short* HSUM  = (short*)(ws + OFF_HSUM);
  float* QAKV  = (float*)(ws + OFF_QAKV);
  short* OH16  = (short*)(ws + OFF_OH);

  // fused f32->bf16 conversions (x, wqa, wkva, wqb, wuv) in ONE launch
  k_cvt5<<<dim3(1024,5), 256, 0, stream>>>(
      x,      X16,                         (long)B_*S_*2048,
      wqa_w,  WQAKV,                       (long)QRANK*2048,
      wkva_w, WQAKV + (long)QRANK*2048,    (long)QKHD*2048,
      wqb_w,  WQB16,                       (long)NH*QKHD*QRANK,
      wuv_w,  WUV16,                       (long)2048*NOPE_);
  // wuk transpose+convert
  k_wukT<<<64, 256, 0, stream>>>(wuk_w, WUKT);

  // merged [qa | kv] = x @ [wqa; wkva]^T  (f32, biases added downstream)
  k_gemm97<64,false><<<dim3(32,27), 256, 0, stream>>>(X16, WQAKV, nullptr, 0.0f, QAKV, 2048, 2048, NMERGE);
  // rms norm (+wqa_b) -> QNORM bf16
  k_rms_q<<<4096, 256, 0, stream>>>(QAKV, wqa_b, qnw, QNORM);
  // kv: +wkva_b, rms, rope, cache merge -> KFULL bf16
  k_kvproc<<<1024, 256, 0, stream>>>(QAKV + QRANK, wkva_b, knw, freqs, cache, sp, KFULL);
  // q = qnorm @ wqb^T + b  -> DIRECTLY into QFULL (layout == q reshaped)
  k_gemm97<128,true><<<dim3(32,24), 256, 0, stream>>>(QNORM, WQB16, wqb_b, 1.0f, QFULL, QRANK, QRANK, NH*QKHD);
  // in-place rope on qfull[...,128:192]
  k_qrope<<<4096, 256, 0, stream>>>(QFULL, freqs);
  // k_abs = k_nope @ wuk  (A = KFULL nope cols, lda=192) -> KQ[...,:128]
  k_gemm97<128,true><<<dim3(32,1), 256, 0, stream>>>(KFULL, WUKT, nullptr, 0.0f, KQ, QKHD, NOPE_, QKHD);
  // KQ rope copy + kb dots
  k_kqfin<<<1024, 256, 0, stream>>>(KFULL, wuk_b, KQ, KB);
  // V transpose -> VT[b][d][t]
  k_vtrans<<<dim3(64,2), 256, 0, stream>>>(KFULL, VT16);
  // flash attention v7 (paired, LDS-staged K/V, kb term)
  k_attn7<<<dim3(16,16,2), 256, 0, stream>>>(QFULL, KQ, VT16, KB, sp, OH16);
  // head sum
  k_redheads<<<512, 256, 0, stream>>>(OH16, HSUM);
  // out = hsum @ wuv^T + 16*b  (f32 -> d_out)
  k_gemm97<64,false><<<dim3(32,32), 256, 0, stream>>>(HSUM, WUV16, wuv_b, 16.0f, (float*)d_out, NOPE_, NOPE_, 2048);
}